// Round 2
// baseline (878.040 us; speedup 1.0000x reference)
//
#include <hip/hip_runtime.h>

typedef _Float16 f16x8 __attribute__((ext_vector_type(8)));
typedef _Float16 f16x4 __attribute__((ext_vector_type(4)));
typedef float f32x4 __attribute__((ext_vector_type(4)));

#define B_SZ 64
#define H_SZ 128
#define S_SZ 4096
#define D_SZ 512
#define PE_SZ 64
#define NCHUNK 4
#define CHUNK 1024
#define NT 32
#define NTILES 32
#define CSCALE 0.06011229381f  // (1/sqrt(576)) * log2(e)

#define STAGE_PITCH 516   // fp32 elems per row (512 + 4 pad), 2064 B
#define KBUF_PITCH 584    // f16 elems per row (576 + 8 pad)
#define VTB_PITCH 40      // f16 elems per row (32 + 8 pad)
#define PB_PITCH 40
#define OB_PITCH 520

#define KBUF_OFF 66048
#define VTB_OFF 103424
#define PB_OFF 144384
#define SMEM_BYTES 154624

// partial workspace layout
#define WSO_BYTES (64ull * 4 * 128 * 512 * 2)   // fp16 partial O = 32 MiB
#define WSM_OFF WSO_BYTES
#define WSL_OFF (WSO_BYTES + 64ull * 4 * 128 * 4)
#define WS_NEEDED (WSO_BYTES + 2ull * 64 * 4 * 128 * 4)

__device__ __forceinline__ void async_copy16(const float* g, float* l) {
  __builtin_amdgcn_global_load_lds(
      (const __attribute__((address_space(1))) void*)g,
      (__attribute__((address_space(3))) void*)l, 16, 0, 0);
}

__launch_bounds__(512, 2)
__global__ void mla_partial(const float* __restrict__ Q, const float* __restrict__ Qpe,
                            const float* __restrict__ KV, const float* __restrict__ Kpe,
                            _Float16* __restrict__ wsO, float* __restrict__ wsM,
                            float* __restrict__ wsL) {
  __shared__ __align__(16) char smem[SMEM_BYTES];
  float* stage   = (float*)smem;                   // [32][516] fp32 KV staging (DMA target)
  _Float16* kbuf = (_Float16*)(smem + KBUF_OFF);   // [32][584] f16 K rows (seq-major, 576 cols)
  _Float16* vtb  = (_Float16*)(smem + VTB_OFF);    // [512][40] f16 V transposed (dim-major)
  _Float16* pb   = (_Float16*)(smem + PB_OFF);     // [8][16][40] per-wave P

  const int tid  = threadIdx.x;
  const int lane = tid & 63;
  const int w    = tid >> 6;
  const int quad = lane >> 4;
  const int l15  = lane & 15;

  const int b  = blockIdx.x >> 2;
  const int c  = blockIdx.x & 3;
  const int s0 = c * CHUNK;

  // ---- Q fragments (A-operand), persistent in registers: head = w*16 + l15 ----
  f16x8 qf[18];
  {
    const int h = w * 16 + l15;
    const float* qrow  = Q   + (size_t)(b * H_SZ + h) * D_SZ;
    const float* qprow = Qpe + (size_t)(b * H_SZ + h) * PE_SZ;
#pragma unroll
    for (int kk = 0; kk < 18; ++kk) {
      const float* src = (kk < 16) ? (qrow + kk * 32 + quad * 8)
                                   : (qprow + (kk - 16) * 32 + quad * 8);
      f32x4 a0 = *(const f32x4*)(src);
      f32x4 a1 = *(const f32x4*)(src + 4);
      f16x8 f;
      f[0] = (_Float16)a0[0]; f[1] = (_Float16)a0[1];
      f[2] = (_Float16)a0[2]; f[3] = (_Float16)a0[3];
      f[4] = (_Float16)a1[0]; f[5] = (_Float16)a1[1];
      f[6] = (_Float16)a1[2]; f[7] = (_Float16)a1[3];
      qf[kk] = f;
    }
  }

  // ---- DMA of one 32-row KV tile into fp32 staging (full-wave only, no predication)
  //      + K_pe tile (2048 contiguous floats) into one f32x4 register per thread ----
  f32x4 kpe_r;
  auto dma_tile = [&](int t, f32x4& kpe_out) {
    const int sg_base = b * S_SZ + s0 + t * NT;
#pragma unroll
    for (int rr = 0; rr < 4; ++rr) {
      const int row = w * 4 + rr;
      const float* gk = KV + (size_t)(sg_base + row) * D_SZ;
      float* l0 = stage + row * STAGE_PITCH;
      async_copy16(gk + lane * 4, l0 + lane * 4);
      async_copy16(gk + 256 + lane * 4, l0 + 256 + lane * 4);
    }
    kpe_out = *(const f32x4*)(Kpe + (size_t)sg_base * PE_SZ + tid * 4);
  };

  // ---- convert staged fp32 -> f16 seq-major K rows + f16 transposed V ----
  auto convert_tile = [&](f32x4 kpe_in) {
    // pass K (KV part): 32 rows x 512 cols, 4-wide chunks
#pragma unroll
    for (int i = 0; i < 8; ++i) {
      int lin  = tid + 512 * i;        // 0..4095
      int row  = lin >> 7;
      int col4 = lin & 127;
      f32x4 v = *(const f32x4*)(stage + row * STAGE_PITCH + col4 * 4);
      f16x4 h;
      h[0] = (_Float16)v[0]; h[1] = (_Float16)v[1];
      h[2] = (_Float16)v[2]; h[3] = (_Float16)v[3];
      *(f16x4*)(kbuf + row * KBUF_PITCH + col4 * 4) = h;
    }
    // pass K (pe part): from registers; tid*4 = (tid>>4)*64 + (tid&15)*4
    {
      int row  = tid >> 4;
      int col4 = tid & 15;
      f16x4 h;
      h[0] = (_Float16)kpe_in[0]; h[1] = (_Float16)kpe_in[1];
      h[2] = (_Float16)kpe_in[2]; h[3] = (_Float16)kpe_in[3];
      *(f16x4*)(kbuf + row * KBUF_PITCH + 512 + col4 * 4) = h;
    }
    // pass V: transpose 4x4 blocks into vtb[dim][seq]
#pragma unroll
    for (int g = 0; g < 2; ++g) {
      int lin   = tid + 512 * g;       // 0..1023
      int rg    = lin & 7;             // row group (4 seq rows)
      int cidx4 = lin >> 3;            // 0..127 (4 dims)
      f32x4 v0 = *(const f32x4*)(stage + (rg * 4 + 0) * STAGE_PITCH + cidx4 * 4);
      f32x4 v1 = *(const f32x4*)(stage + (rg * 4 + 1) * STAGE_PITCH + cidx4 * 4);
      f32x4 v2 = *(const f32x4*)(stage + (rg * 4 + 2) * STAGE_PITCH + cidx4 * 4);
      f32x4 v3 = *(const f32x4*)(stage + (rg * 4 + 3) * STAGE_PITCH + cidx4 * 4);
#pragma unroll
      for (int u = 0; u < 4; ++u) {
        f16x4 h;
        h[0] = (_Float16)v0[u]; h[1] = (_Float16)v1[u];
        h[2] = (_Float16)v2[u]; h[3] = (_Float16)v3[u];
        *(f16x4*)(vtb + (cidx4 * 4 + u) * VTB_PITCH + rg * 4) = h;
      }
    }
  };

  // ---- accumulators / softmax state ----
  f32x4 O[32];
#pragma unroll
  for (int i = 0; i < 32; ++i) O[i] = (f32x4){0.f, 0.f, 0.f, 0.f};
  f32x4 mr = (f32x4){-1e30f, -1e30f, -1e30f, -1e30f};
  f32x4 lr = (f32x4){0.f, 0.f, 0.f, 0.f};

  dma_tile(0, kpe_r);
  __syncthreads();   // drains DMA(0)
  convert_tile(kpe_r);
  __syncthreads();

  _Float16* pw = pb + w * 16 * PB_PITCH;

#pragma unroll 1
  for (int t = 0; t < NTILES; ++t) {
    f32x4 kpe_nxt;
    if (t < NTILES - 1) dma_tile(t + 1, kpe_nxt);  // async; consumed after barrier

    // ---- QK^T: S tile 16 heads x 32 seq ----
    f32x4 S0 = (f32x4){0.f, 0.f, 0.f, 0.f};
    f32x4 S1 = (f32x4){0.f, 0.f, 0.f, 0.f};
#pragma unroll
    for (int kk = 0; kk < 18; ++kk) {
      f16x8 b0 = *(const f16x8*)(kbuf + l15 * KBUF_PITCH + kk * 32 + quad * 8);
      f16x8 b1 = *(const f16x8*)(kbuf + (16 + l15) * KBUF_PITCH + kk * 32 + quad * 8);
      S0 = __builtin_amdgcn_mfma_f32_16x16x32_f16(qf[kk], b0, S0, 0, 0, 0);
      S1 = __builtin_amdgcn_mfma_f32_16x16x32_f16(qf[kk], b1, S1, 0, 0, 0);
    }

    // ---- online softmax (rows = heads = quad*4+i, cols across l15) ----
    f32x4 mx;
#pragma unroll
    for (int i = 0; i < 4; ++i) mx[i] = fmaxf(S0[i], S1[i]);
#pragma unroll
    for (int m = 1; m <= 8; m <<= 1) {
#pragma unroll
      for (int i = 0; i < 4; ++i) mx[i] = fmaxf(mx[i], __shfl_xor(mx[i], m, 64));
    }
    f32x4 mn, al, P0, P1, rs;
#pragma unroll
    for (int i = 0; i < 4; ++i) {
      mn[i] = fmaxf(mr[i], mx[i]);
      al[i] = exp2f((mr[i] - mn[i]) * CSCALE);
      P0[i] = exp2f((S0[i] - mn[i]) * CSCALE);
      P1[i] = exp2f((S1[i] - mn[i]) * CSCALE);
      rs[i] = P0[i] + P1[i];
    }
#pragma unroll
    for (int m = 1; m <= 8; m <<= 1) {
#pragma unroll
      for (int i = 0; i < 4; ++i) rs[i] += __shfl_xor(rs[i], m, 64);
    }
#pragma unroll
    for (int i = 0; i < 4; ++i) {
      lr[i] = lr[i] * al[i] + rs[i];
      mr[i] = mn[i];
    }

    // ---- write P (f16) to per-wave LDS, rescale O ----
#pragma unroll
    for (int i = 0; i < 4; ++i) {
      pw[(quad * 4 + i) * PB_PITCH + l15]      = (_Float16)P0[i];
      pw[(quad * 4 + i) * PB_PITCH + 16 + l15] = (_Float16)P1[i];
    }
#pragma unroll
    for (int nt = 0; nt < 32; ++nt) O[nt] *= al;

    // ---- PV: O += P @ V (K = 32 seq) ----
    f16x8 pa = *(const f16x8*)(pw + l15 * PB_PITCH + quad * 8);
#pragma unroll
    for (int nt = 0; nt < 32; ++nt) {
      f16x8 bv = *(const f16x8*)(vtb + (nt * 16 + l15) * VTB_PITCH + quad * 8);
      O[nt] = __builtin_amdgcn_mfma_f32_16x16x32_f16(pa, bv, O[nt], 0, 0, 0);
    }

    __syncthreads();   // all waves done with kbuf/vtb(t); DMA(t+1) drained
    if (t < NTILES - 1) {
      convert_tile(kpe_nxt);
      __syncthreads();
    }
  }

  // ---- epilogue: normalize, transpose via LDS, coalesced f16 store ----
  f32x4 inv;
#pragma unroll
  for (int i = 0; i < 4; ++i) inv[i] = 1.0f / lr[i];

  _Float16* ob = (_Float16*)smem;   // [128][520]
#pragma unroll
  for (int nt = 0; nt < 32; ++nt) {
#pragma unroll
    for (int i = 0; i < 4; ++i) {
      ob[(w * 16 + quad * 4 + i) * OB_PITCH + nt * 16 + l15] =
          (_Float16)(O[nt][i] * inv[i]);
    }
  }
  __syncthreads();
  const size_t obase = (size_t)blockIdx.x * H_SZ * D_SZ;
#pragma unroll
  for (int j = 0; j < 16; ++j) {
    int idx = tid + 512 * j;        // 0..8191
    int h   = idx >> 6;
    int d8  = (idx & 63) * 8;
    f16x8 v = *(const f16x8*)(ob + h * OB_PITCH + d8);
    *(f16x8*)(wsO + obase + h * D_SZ + d8) = v;
  }
  if (l15 == 0) {
    const int sbase = blockIdx.x * H_SZ + w * 16 + quad * 4;
#pragma unroll
    for (int i = 0; i < 4; ++i) {
      wsM[sbase + i] = mr[i];
      wsL[sbase + i] = lr[i];
    }
  }
}

__global__ void mla_combine(const _Float16* __restrict__ wsO, const float* __restrict__ wsM,
                            const float* __restrict__ wsL, float* __restrict__ out) {
  int tidg = blockIdx.x * 256 + threadIdx.x;   // 0..524287
  int row  = tidg >> 6;                        // b*128+h
  int d8   = (tidg & 63) * 8;
  int b    = row >> 7;
  int h    = row & 127;

  float mv[4], lv[4];
#pragma unroll
  for (int c = 0; c < 4; ++c) {
    mv[c] = wsM[(b * 4 + c) * 128 + h];
    lv[c] = wsL[(b * 4 + c) * 128 + h];
  }
  float M = fmaxf(fmaxf(mv[0], mv[1]), fmaxf(mv[2], mv[3]));
  float wv[4], wsum = 0.f;
#pragma unroll
  for (int c = 0; c < 4; ++c) {
    wv[c] = lv[c] * exp2f((mv[c] - M) * CSCALE);
    wsum += wv[c];
  }
  float o[8] = {0.f, 0.f, 0.f, 0.f, 0.f, 0.f, 0.f, 0.f};
#pragma unroll
  for (int c = 0; c < 4; ++c) {
    f16x8 v = *(const f16x8*)(wsO + (size_t)((b * 4 + c) * 128 + h) * 512 + d8);
#pragma unroll
    for (int j = 0; j < 8; ++j) o[j] += wv[c] * (float)v[j];
  }
  float r = 1.0f / wsum;
  f32x4 r0 = (f32x4){o[0] * r, o[1] * r, o[2] * r, o[3] * r};
  f32x4 r1 = (f32x4){o[4] * r, o[5] * r, o[6] * r, o[7] * r};
  *(f32x4*)(out + (size_t)row * 512 + d8) = r0;
  *(f32x4*)(out + (size_t)row * 512 + d8 + 4) = r1;
}

extern "C" void kernel_launch(void* const* d_in, const int* in_sizes, int n_in,
                              void* d_out, int out_size, void* d_ws, size_t ws_size,
                              hipStream_t stream) {
  if (ws_size < WS_NEEDED) return;   // fail loudly (output left poisoned)
  const float* Q   = (const float*)d_in[0];
  const float* Qpe = (const float*)d_in[1];
  const float* KV  = (const float*)d_in[2];
  const float* Kpe = (const float*)d_in[3];
  _Float16* wsO = (_Float16*)d_ws;
  float* wsM = (float*)((char*)d_ws + WSM_OFF);
  float* wsL = (float*)((char*)d_ws + WSL_OFF);

  mla_partial<<<dim3(B_SZ * NCHUNK), dim3(512), 0, stream>>>(Q, Qpe, KV, Kpe, wsO, wsM, wsL);
  mla_combine<<<dim3(2048), dim3(256), 0, stream>>>(wsO, wsM, wsL, (float*)d_out);
}